// Round 1
// baseline (861.912 us; speedup 1.0000x reference)
//
#include <hip/hip_runtime.h>

static constexpr int IMG  = 2048;   // H = W
static constexpr int CH   = 3;
static constexpr int KS   = 25;     // PSF size
static constexpr int HALO = 12;     // KS/2
static constexpr int DN   = 512;    // downsampled size (IMG/4)
static constexpr int PD   = 18;     // taps, downsample (kw=16 -> ceil+2)
static constexpr int PU   = 6;      // taps, upsample  (kw=4  -> ceil+2)
static constexpr float LAM = 0.1f;

// ---------------------------------------------------------------------------
// Bicubic resize weight tables (matches MATLAB-style imresize in the ref).
// Computed on-device in double, every call (same work every call).
// ---------------------------------------------------------------------------
__device__ __forceinline__ double cubic_d(double x) {
  double ax = fabs(x), ax2 = ax * ax, ax3 = ax2 * ax;
  if (ax <= 1.0) return 1.5 * ax3 - 2.5 * ax2 + 1.0;
  if (ax <= 2.0) return -0.5 * ax3 + 2.5 * ax2 - 4.0 * ax + 2.0;
  return 0.0;
}

__global__ void build_tables(float* dwW, int* dwI, float* uwW, int* uwI) {
  int i = blockIdx.x * blockDim.x + threadIdx.x;
  if (i < DN) {
    // downsample: in 2048 -> out 512, scale 0.25, widened kernel kw = 16
    const double scale = 0.25;
    double u = (double)(i + 1) / scale + 0.5 * (1.0 - 1.0 / scale); // 4(i+1)-1.5
    double left = floor(u - 8.0);
    double w[PD]; int id[PD]; double s = 0.0;
    for (int p = 0; p < PD; ++p) {
      double ind = left + p;
      w[p] = scale * cubic_d(scale * (u - ind));
      s += w[p];
      long long m = ((long long)ind - 1) % (2 * IMG);
      if (m < 0) m += 2 * IMG;
      id[p] = (m < IMG) ? (int)m : (int)(2 * IMG - 1 - m);  // mirror
    }
    for (int p = 0; p < PD; ++p) {
      dwW[i * PD + p] = (float)(w[p] / s);
      dwI[i * PD + p] = id[p];
    }
  }
  if (i < IMG) {
    // upsample: in 512 -> out 2048, scale 4, kw = 4
    const double scale = 4.0;
    double u = (double)(i + 1) / scale + 0.5 * (1.0 - 1.0 / scale); // (i+1)/4+0.375
    double left = floor(u - 2.0);
    double w[PU]; int id[PU]; double s = 0.0;
    for (int p = 0; p < PU; ++p) {
      double ind = left + p;
      w[p] = cubic_d(u - ind);
      s += w[p];
      long long m = ((long long)ind - 1) % (2 * DN);
      if (m < 0) m += 2 * DN;
      id[p] = (m < DN) ? (int)m : (int)(2 * DN - 1 - m);
    }
    for (int p = 0; p < PU; ++p) {
      uwW[i * PU + p] = (float)(w[p] / s);
      uwI[i * PU + p] = id[p];
    }
  }
}

// ---------------------------------------------------------------------------
// 25x25 circular cross-correlation, fp32.
// FLIP=1: weight = k[24-ky][24-kx]  (== circular convolution with k)
// FLIP=0: weight = k[ky][kx]        (plain cross-correlation)
// Tile: 128x16 outputs / block (256 threads, 8 outputs in x per thread).
// ---------------------------------------------------------------------------
template <int FLIP>
__global__ __launch_bounds__(256) void corr25(const float* __restrict__ src,
                                              const float* __restrict__ kw,
                                              float* __restrict__ dst) {
  constexpr int TW = 128, TH = 16;
  constexpr int IW = TW + KS - 1;  // 152
  constexpr int IH = TH + KS - 1;  // 40
  __shared__ float tile[IH][IW];   // 24320 B

  const int tid = threadIdx.x;
  const int c   = blockIdx.z;
  const int x0  = blockIdx.x * TW;
  const int y0  = blockIdx.y * TH;
  const float* s = src + (size_t)c * IMG * IMG;

  // stage input tile (wrap boundary via & since IMG is pow2)
  for (int i = tid; i < IH * IW; i += 256) {
    int r   = i / IW;
    int col = i - r * IW;
    int gy  = (y0 + r   - HALO) & (IMG - 1);
    int gx  = (x0 + col - HALO) & (IMG - 1);
    tile[r][col] = s[(size_t)gy * IMG + gx];
  }
  __syncthreads();

  const int tx = tid & 15;
  const int ty = tid >> 4;
  const int ox = tx * 8;

  float acc[8];
#pragma unroll
  for (int o = 0; o < 8; ++o) acc[o] = 0.f;

#pragma unroll 1
  for (int ky = 0; ky < KS; ++ky) {
    const float* t = &tile[ty + ky][ox];
    float row[32];
#pragma unroll
    for (int j = 0; j < 8; ++j) {
      float4 v = *reinterpret_cast<const float4*>(t + 4 * j);
      row[4 * j + 0] = v.x; row[4 * j + 1] = v.y;
      row[4 * j + 2] = v.z; row[4 * j + 3] = v.w;
    }
#pragma unroll
    for (int kx = 0; kx < KS; ++kx) {
      float w = FLIP ? kw[(KS - 1 - ky) * KS + (KS - 1 - kx)]
                     : kw[ky * KS + kx];
#pragma unroll
      for (int o = 0; o < 8; ++o)
        acc[o] = fmaf(w, row[kx + o], acc[o]);
    }
  }

  float* d = dst + (size_t)c * IMG * IMG + (size_t)(y0 + ty) * IMG + x0 + ox;
  *reinterpret_cast<float4*>(d)     = make_float4(acc[0], acc[1], acc[2], acc[3]);
  *reinterpret_cast<float4*>(d + 4) = make_float4(acc[4], acc[5], acc[6], acc[7]);
}

// ---------------------------------------------------------------------------
// Separable bicubic resize passes
// ---------------------------------------------------------------------------
__global__ void rows_down(const float* __restrict__ src, float* __restrict__ dst,
                          const float* __restrict__ wW, const int* __restrict__ wI) {
  int x = blockIdx.x * blockDim.x + threadIdx.x;  // 0..2047
  int o = blockIdx.y;                             // 0..511
  int c = blockIdx.z;
  const float* s = src + (size_t)c * IMG * IMG;
  float acc = 0.f;
#pragma unroll
  for (int p = 0; p < PD; ++p)
    acc = fmaf(wW[o * PD + p], s[(size_t)wI[o * PD + p] * IMG + x], acc);
  dst[((size_t)c * DN + o) * IMG + x] = acc;
}

__global__ void cols_down(const float* __restrict__ src, float* __restrict__ dst,
                          const float* __restrict__ wW, const int* __restrict__ wI) {
  int o = blockIdx.x * blockDim.x + threadIdx.x;  // 0..511 (output col)
  int y = blockIdx.y;                             // 0..511
  int c = blockIdx.z;
  const float* s = src + ((size_t)c * DN + y) * IMG;
  float acc = 0.f;
#pragma unroll
  for (int p = 0; p < PD; ++p)
    acc = fmaf(wW[o * PD + p], s[wI[o * PD + p]], acc);
  dst[((size_t)c * DN + y) * DN + o] = acc;
}

__global__ void rows_up(const float* __restrict__ src, float* __restrict__ dst,
                        const float* __restrict__ wW, const int* __restrict__ wI) {
  int x = blockIdx.x * blockDim.x + threadIdx.x;  // 0..511
  int o = blockIdx.y;                             // 0..2047
  int c = blockIdx.z;
  const float* s = src + (size_t)c * DN * DN;
  float acc = 0.f;
#pragma unroll
  for (int p = 0; p < PU; ++p)
    acc = fmaf(wW[o * PU + p], s[(size_t)wI[o * PU + p] * DN + x], acc);
  dst[((size_t)c * IMG + o) * DN + x] = acc;
}

__global__ void cols_up_add(const float* __restrict__ src, float* __restrict__ out,
                            const float* __restrict__ wW, const int* __restrict__ wI) {
  int x = blockIdx.x * blockDim.x + threadIdx.x;  // 0..2047
  int y = blockIdx.y;                             // 0..2047
  int c = blockIdx.z;
  const float* s = src + ((size_t)c * IMG + y) * DN;
  float acc = 0.f;
#pragma unroll
  for (int p = 0; p < PU; ++p)
    acc = fmaf(wW[x * PU + p], s[wI[x * PU + p]], acc);
  size_t oi = ((size_t)c * IMG + y) * IMG + x;
  out[oi] = fmaf(LAM, acc, out[oi]);
}

// ---------------------------------------------------------------------------
extern "C" void kernel_launch(void* const* d_in, const int* in_sizes, int n_in,
                              void* d_out, int out_size, void* d_ws, size_t ws_size,
                              hipStream_t stream) {
  const float* im  = (const float*)d_in[0];
  const float* ker = (const float*)d_in[1];
  float* out = (float*)d_out;
  float* ws  = (float*)d_ws;

  const size_t NIM = (size_t)CH * IMG * IMG;  // 12.58M floats

  // ws layout:
  //   [0, NIM)          : ax (pass A output) -- later reused for t1/t2/t3
  //   [NIM, NIM+43008)  : weight tables
  float* ax = ws;
  float* t1 = ws;                              // (C,512,2048) after ax is dead
  float* t2 = t1 + (size_t)CH * DN * IMG;      // (C,512,512)
  float* t3 = t2 + (size_t)CH * DN * DN;       // (C,2048,512)
  float* dwW = ws + NIM;
  int*   dwI = (int*)(dwW + DN * PD);
  float* uwW = (float*)(dwI + DN * PD);
  int*   uwI = (int*)(uwW + (size_t)IMG * PU);

  build_tables<<<(IMG + 255) / 256, 256, 0, stream>>>(dwW, dwI, uwW, uwI);

  // A^T A x: two 25x25 circular correlations (flipped, then plain)
  dim3 cgrid(IMG / 128, IMG / 16, CH);
  corr25<1><<<cgrid, 256, 0, stream>>>(im, ker, ax);
  corr25<0><<<cgrid, 256, 0, stream>>>(ax, ker, out);

  // 0.1 * H^T H x: 4 separable bicubic passes, accumulate into out
  rows_down  <<<dim3(IMG / 256, DN,  CH), 256, 0, stream>>>(im, t1, dwW, dwI);
  cols_down  <<<dim3(DN  / 256, DN,  CH), 256, 0, stream>>>(t1, t2, dwW, dwI);
  rows_up    <<<dim3(DN  / 256, IMG, CH), 256, 0, stream>>>(t2, t3, uwW, uwI);
  cols_up_add<<<dim3(IMG / 256, IMG, CH), 256, 0, stream>>>(t3, out, uwW, uwI);
}

// Round 4
// 471.870 us; speedup vs baseline: 1.8266x; 1.8266x over previous
//
#include <hip/hip_runtime.h>

static constexpr int IMG  = 2048;   // H = W
static constexpr int CH   = 3;
static constexpr int KS   = 25;     // PSF size
static constexpr int HALO = 12;     // KS/2
static constexpr int DN   = 512;    // downsampled size (IMG/4)
static constexpr int PD   = 18;     // taps, downsample (kw=16 -> ceil+2)
static constexpr int PU   = 6;      // taps, upsample  (kw=4  -> ceil+2)
static constexpr float LAM = 0.1f;

// ---------------------------------------------------------------------------
// Bicubic resize weight tables (matches MATLAB-style imresize in the ref).
// ---------------------------------------------------------------------------
__device__ __forceinline__ double cubic_d(double x) {
  double ax = fabs(x), ax2 = ax * ax, ax3 = ax2 * ax;
  if (ax <= 1.0) return 1.5 * ax3 - 2.5 * ax2 + 1.0;
  if (ax <= 2.0) return -0.5 * ax3 + 2.5 * ax2 - 4.0 * ax + 2.0;
  return 0.0;
}

__global__ void build_tables(float* dwW, int* dwI, float* uwW, int* uwI) {
  int i = blockIdx.x * blockDim.x + threadIdx.x;
  if (i < DN) {
    const double scale = 0.25;
    double u = (double)(i + 1) / scale + 0.5 * (1.0 - 1.0 / scale);
    double left = floor(u - 8.0);
    double w[PD]; int id[PD]; double s = 0.0;
    for (int p = 0; p < PD; ++p) {
      double ind = left + p;
      w[p] = scale * cubic_d(scale * (u - ind));
      s += w[p];
      long long m = ((long long)ind - 1) % (2 * IMG);
      if (m < 0) m += 2 * IMG;
      id[p] = (m < IMG) ? (int)m : (int)(2 * IMG - 1 - m);
    }
    for (int p = 0; p < PD; ++p) {
      dwW[i * PD + p] = (float)(w[p] / s);
      dwI[i * PD + p] = id[p];
    }
  }
  if (i < IMG) {
    const double scale = 4.0;
    double u = (double)(i + 1) / scale + 0.5 * (1.0 - 1.0 / scale);
    double left = floor(u - 2.0);
    double w[PU]; int id[PU]; double s = 0.0;
    for (int p = 0; p < PU; ++p) {
      double ind = left + p;
      w[p] = cubic_d(u - ind);
      s += w[p];
      long long m = ((long long)ind - 1) % (2 * DN);
      if (m < 0) m += 2 * DN;
      id[p] = (m < DN) ? (int)m : (int)(2 * DN - 1 - m);
    }
    for (int p = 0; p < PU; ++p) {
      uwW[i * PU + p] = (float)(w[p] / s);
      uwI[i * PU + p] = id[p];
    }
  }
}

// ---------------------------------------------------------------------------
// 25x25 circular cross-correlation, fp32.
// FLIP=1: weight = k[24-ky][24-kx], FLIP=0: weight = k[ky][kx].
// Tile: 128x32 outputs / 256 threads; each thread: 8x * 2y outputs.
// LDS: 56x160 (padded from 152; stride 160 == 0 mod 32 banks) with XOR
// swizzle col ^= ((r>>1)&7)<<2 -> wave64 ds_read_b128 hits every bank
// exactly 8x (the minimum).  >>1 because thread rows are y-stride-2.
// ---------------------------------------------------------------------------
template <int FLIP>
__global__ __launch_bounds__(256, 4) void corr25(const float* __restrict__ src,
                                                 const float* __restrict__ kw,
                                                 float* __restrict__ dst) {
  constexpr int TW = 128, TH = 32;
  constexpr int SW = 160;             // padded staged width (152 valid cols)
  constexpr int SH = TH + KS - 1;     // 56
  constexpr int CHUNKS = 152 / 4;     // 38 float4 chunks per staged row
  __shared__ float tile[SH][SW];      // 35840 B -> 4 blocks/CU

  const int tid = threadIdx.x;
  const int c   = blockIdx.z;
  const int x0  = blockIdx.x * TW;
  const int y0  = blockIdx.y * TH;
  const float* s = src + (size_t)c * IMG * IMG;

  // ---- stage (float4 chunks, swizzled writes) ----
  const bool xwrap = (x0 < HALO) || (x0 + TW + HALO > IMG);
  for (int ci = tid; ci < SH * CHUNKS; ci += 256) {
    int r  = ci / CHUNKS;
    int cj = ci - r * CHUNKS;
    int gy = (y0 + r - HALO) & (IMG - 1);
    int col  = 4 * cj;
    int scol = col ^ (((r >> 1) & 7) << 2);
    float4 v;
    if (!xwrap) {
      v = *reinterpret_cast<const float4*>(&s[(size_t)gy * IMG + (x0 - HALO + col)]);
    } else {
      int gx = x0 - HALO + col;
      v.x = s[(size_t)gy * IMG + ((gx + 0) & (IMG - 1))];
      v.y = s[(size_t)gy * IMG + ((gx + 1) & (IMG - 1))];
      v.z = s[(size_t)gy * IMG + ((gx + 2) & (IMG - 1))];
      v.w = s[(size_t)gy * IMG + ((gx + 3) & (IMG - 1))];
    }
    *reinterpret_cast<float4*>(&tile[r][scol]) = v;
  }
  __syncthreads();

  const int tx    = tid & 15;
  const int tyt   = tid >> 4;
  const int ox    = tx * 8;
  const int rbase = tyt * 2;          // this thread's first output row (local)

  float acc0[8], acc1[8];
#pragma unroll
  for (int o = 0; o < 8; ++o) { acc0[o] = 0.f; acc1[o] = 0.f; }

#pragma unroll 2
  for (int rr = 0; rr < KS + 1; ++rr) {   // 26 staged row-strips per thread
    const int r   = rbase + rr;
    const int swz = ((r >> 1) & 7) << 2;
    float row[32];
#pragma unroll
    for (int j = 0; j < 8; ++j) {
      float4 v = *reinterpret_cast<const float4*>(&tile[r][(ox + 4 * j) ^ swz]);
      row[4 * j + 0] = v.x; row[4 * j + 1] = v.y;
      row[4 * j + 2] = v.z; row[4 * j + 3] = v.w;
    }
    if (rr <= KS - 1) {                 // dy = 0 : ky = rr
      const int ky = rr;
#pragma unroll
      for (int kx = 0; kx < KS; ++kx) {
        float w = FLIP ? kw[(KS - 1 - ky) * KS + (KS - 1 - kx)]
                       : kw[ky * KS + kx];
#pragma unroll
        for (int o = 0; o < 8; ++o) acc0[o] = fmaf(w, row[kx + o], acc0[o]);
      }
    }
    if (rr >= 1) {                      // dy = 1 : ky = rr - 1
      const int ky = rr - 1;
#pragma unroll
      for (int kx = 0; kx < KS; ++kx) {
        float w = FLIP ? kw[(KS - 1 - ky) * KS + (KS - 1 - kx)]
                       : kw[ky * KS + kx];
#pragma unroll
        for (int o = 0; o < 8; ++o) acc1[o] = fmaf(w, row[kx + o], acc1[o]);
      }
    }
  }

  float* d0 = dst + (size_t)c * IMG * IMG + (size_t)(y0 + rbase) * IMG + x0 + ox;
  *reinterpret_cast<float4*>(d0)           = make_float4(acc0[0], acc0[1], acc0[2], acc0[3]);
  *reinterpret_cast<float4*>(d0 + 4)       = make_float4(acc0[4], acc0[5], acc0[6], acc0[7]);
  *reinterpret_cast<float4*>(d0 + IMG)     = make_float4(acc1[0], acc1[1], acc1[2], acc1[3]);
  *reinterpret_cast<float4*>(d0 + IMG + 4) = make_float4(acc1[4], acc1[5], acc1[6], acc1[7]);
}

// ---------------------------------------------------------------------------
// Separable bicubic resize passes (unchanged; ~80 us total)
// ---------------------------------------------------------------------------
__global__ void rows_down(const float* __restrict__ src, float* __restrict__ dst,
                          const float* __restrict__ wW, const int* __restrict__ wI) {
  int x = blockIdx.x * blockDim.x + threadIdx.x;
  int o = blockIdx.y;
  int c = blockIdx.z;
  const float* s = src + (size_t)c * IMG * IMG;
  float acc = 0.f;
#pragma unroll
  for (int p = 0; p < PD; ++p)
    acc = fmaf(wW[o * PD + p], s[(size_t)wI[o * PD + p] * IMG + x], acc);
  dst[((size_t)c * DN + o) * IMG + x] = acc;
}

__global__ void cols_down(const float* __restrict__ src, float* __restrict__ dst,
                          const float* __restrict__ wW, const int* __restrict__ wI) {
  int o = blockIdx.x * blockDim.x + threadIdx.x;
  int y = blockIdx.y;
  int c = blockIdx.z;
  const float* s = src + ((size_t)c * DN + y) * IMG;
  float acc = 0.f;
#pragma unroll
  for (int p = 0; p < PD; ++p)
    acc = fmaf(wW[o * PD + p], s[wI[o * PD + p]], acc);
  dst[((size_t)c * DN + y) * DN + o] = acc;
}

__global__ void rows_up(const float* __restrict__ src, float* __restrict__ dst,
                        const float* __restrict__ wW, const int* __restrict__ wI) {
  int x = blockIdx.x * blockDim.x + threadIdx.x;
  int o = blockIdx.y;
  int c = blockIdx.z;
  const float* s = src + (size_t)c * DN * DN;
  float acc = 0.f;
#pragma unroll
  for (int p = 0; p < PU; ++p)
    acc = fmaf(wW[o * PU + p], s[(size_t)wI[o * PU + p] * DN + x], acc);
  dst[((size_t)c * IMG + o) * DN + x] = acc;
}

__global__ void cols_up_add(const float* __restrict__ src, float* __restrict__ out,
                            const float* __restrict__ wW, const int* __restrict__ wI) {
  int x = blockIdx.x * blockDim.x + threadIdx.x;
  int y = blockIdx.y;
  int c = blockIdx.z;
  const float* s = src + ((size_t)c * IMG + y) * DN;
  float acc = 0.f;
#pragma unroll
  for (int p = 0; p < PU; ++p)
    acc = fmaf(wW[x * PU + p], s[wI[x * PU + p]], acc);
  size_t oi = ((size_t)c * IMG + y) * IMG + x;
  out[oi] = fmaf(LAM, acc, out[oi]);
}

// ---------------------------------------------------------------------------
extern "C" void kernel_launch(void* const* d_in, const int* in_sizes, int n_in,
                              void* d_out, int out_size, void* d_ws, size_t ws_size,
                              hipStream_t stream) {
  const float* im  = (const float*)d_in[0];
  const float* ker = (const float*)d_in[1];
  float* out = (float*)d_out;
  float* ws  = (float*)d_ws;

  const size_t NIM = (size_t)CH * IMG * IMG;

  // ws layout (proven footprint ~50.5 MB):
  //   [0, NIM)   : ax (pass A output) -- later reused for t1/t2/t3
  //   [NIM, ...) : weight tables
  float* ax = ws;
  float* t1 = ws;
  float* t2 = t1 + (size_t)CH * DN * IMG;
  float* t3 = t2 + (size_t)CH * DN * DN;
  float* dwW = ws + NIM;
  int*   dwI = (int*)(dwW + DN * PD);
  float* uwW = (float*)(dwI + DN * PD);
  int*   uwI = (int*)(uwW + (size_t)IMG * PU);

  build_tables<<<(IMG + 255) / 256, 256, 0, stream>>>(dwW, dwI, uwW, uwI);

  // A^T A x: two 25x25 circular correlations (flipped, then plain)
  dim3 cgrid(IMG / 128, IMG / 32, CH);
  corr25<1><<<cgrid, 256, 0, stream>>>(im, ker, ax);
  corr25<0><<<cgrid, 256, 0, stream>>>(ax, ker, out);

  // 0.1 * H^T H x: 4 separable bicubic passes, accumulate into out
  rows_down  <<<dim3(IMG / 256, DN,  CH), 256, 0, stream>>>(im, t1, dwW, dwI);
  cols_down  <<<dim3(DN  / 256, DN,  CH), 256, 0, stream>>>(t1, t2, dwW, dwI);
  rows_up    <<<dim3(DN  / 256, IMG, CH), 256, 0, stream>>>(t2, t3, uwW, uwI);
  cols_up_add<<<dim3(IMG / 256, IMG, CH), 256, 0, stream>>>(t3, out, uwW, uwI);
}